// Round 1
// 587.910 us; speedup vs baseline: 1.7827x; 1.7827x over previous
//
#include <hip/hip_runtime.h>
#include <hip/hip_fp16.h>
#include <math.h>

// Sinkhorn-Knopp, linear domain with reciprocals. B=8, n=2048, TAU=1, 20 iters.
//
// Iterate needs only rinv[i] = 1/rowsum, invS[j] = 1/colsum:
//   rowsum_i = sum_j exp(la_ij) * invS_j   (invS = 1 on first pass)
//   colsum_j = sum_i exp(la_ij) * rinv_i   (uses the NEW rinv)
// Since rinv_i depends only on row i, the row sum and this row's column
// contributions fuse into ONE kernel: la is read once per iteration (20
// sweeps of the 64 MB fp16 matrix instead of 40). exp(la) is computed once
// per element per iteration and reused for both phases from registers.
// No overflow: la ~ N(0,1) so exp(la) <= ~300; all sums are O(1e4) in fp32.

constexpr int Nn = 2048;
constexpr int Bb = 8;
constexpr long long TOT = (long long)Bb * Nn * Nn;
constexpr int CHUNKS = 64;                        // row chunks per batch
constexpr int ROWS_PER_CHUNK = Nn / CHUNKS;       // 32
constexpr int ROWS_PER_WAVE = ROWS_PER_CHUNK / 4; // 8

using half8   = __attribute__((ext_vector_type(8))) _Float16;
using float8v = __attribute__((ext_vector_type(8))) float;

template<typename T> struct V8;
template<> struct V8<float>    { using type = float8v; };
template<> struct V8<_Float16> { using type = half8;   };

// la16 = (fp16) la0
__global__ __launch_bounds__(256) void convert_f16(const float* __restrict__ in,
                                                   _Float16* __restrict__ out) {
  const size_t g = (size_t)blockIdx.x * 256 + threadIdx.x;   // group of 8
  float4 a = ((const float4*)in)[g * 2];
  float4 b = ((const float4*)in)[g * 2 + 1];
  half8 h;
  h[0] = (_Float16)a.x; h[1] = (_Float16)a.y; h[2] = (_Float16)a.z; h[3] = (_Float16)a.w;
  h[4] = (_Float16)b.x; h[5] = (_Float16)b.y; h[6] = (_Float16)b.z; h[7] = (_Float16)b.w;
  ((half8*)out)[g] = h;
}

// Fused row+col pass. grid = (CHUNKS, Bb) = 512 blocks, 256 threads.
// Each wave owns 8 rows sequentially; lane owns 4 groups of 8 columns
// (cols (k*64+lane)*8 .. +8). Row data held in regs between phases.
template<typename T, bool FIRST>
__global__ __launch_bounds__(256) void fused_pass(const T* __restrict__ la,
                                                  const float* __restrict__ invS,
                                                  float* __restrict__ rinv,
                                                  float* __restrict__ partial) {
  using v8 = typename V8<T>::type;
  const int lane  = threadIdx.x & 63;
  const int wave  = threadIdx.x >> 6;
  const int chunk = blockIdx.x;
  const int b     = blockIdx.y;

  float is[4][8];
  if (!FIRST) {
    const float4* __restrict__ c4 = (const float4*)(invS + (size_t)b * Nn);
#pragma unroll
    for (int k = 0; k < 4; ++k) {
      const int g = (k << 6) + lane;
      float4 a = c4[g * 2], c = c4[g * 2 + 1];
      is[k][0] = a.x; is[k][1] = a.y; is[k][2] = a.z; is[k][3] = a.w;
      is[k][4] = c.x; is[k][5] = c.y; is[k][6] = c.z; is[k][7] = c.w;
    }
  }

  float acc[4][8] = {{0.f}};
  const int r0 = chunk * ROWS_PER_CHUNK + wave * ROWS_PER_WAVE;
  const T* __restrict__ lab = la + (size_t)b * Nn * Nn;

#pragma unroll 2
  for (int i = 0; i < ROWS_PER_WAVE; ++i) {
    const int r = r0 + i;
    const v8* __restrict__ row8 = (const v8*)(lab + (size_t)r * Nn);
    float e[4][8];
    float s = 0.f;
#pragma unroll
    for (int k = 0; k < 4; ++k) {
      v8 v = row8[(k << 6) + lane];
#pragma unroll
      for (int el = 0; el < 8; ++el) {
        const float ex = __expf((float)v[el]);
        e[k][el] = ex;
        s = FIRST ? (s + ex) : fmaf(ex, is[k][el], s);
      }
    }
#pragma unroll
    for (int off = 32; off >= 1; off >>= 1) s += __shfl_xor(s, off);
    const float ri = 1.f / s;
    if (lane == 0) rinv[(size_t)b * Nn + r] = ri;
#pragma unroll
    for (int k = 0; k < 4; ++k)
#pragma unroll
      for (int el = 0; el < 8; ++el) acc[k][el] += e[k][el] * ri;
  }

  // Cross-wave column reduce. sm[srcWave][ke][lane]: lane-contiguous on both
  // write and read -> conflict-free. 32 KB (2 blocks/CU -> 64 KB of 160).
  __shared__ float sm[4][32][64];
#pragma unroll
  for (int k = 0; k < 4; ++k)
#pragma unroll
    for (int el = 0; el < 8; ++el) sm[wave][k * 8 + el][lane] = acc[k][el];
  __syncthreads();

  // Wave w combines column-group k = w and writes its 2 KB partial slice.
  float o[8];
#pragma unroll
  for (int el = 0; el < 8; ++el)
    o[el] = (sm[0][wave * 8 + el][lane] + sm[1][wave * 8 + el][lane]) +
            (sm[2][wave * 8 + el][lane] + sm[3][wave * 8 + el][lane]);
  float* dst = partial + ((size_t)chunk * Bb + b) * Nn + ((wave << 6) + lane) * 8;
  ((float4*)dst)[0] = make_float4(o[0], o[1], o[2], o[3]);
  ((float4*)dst)[1] = make_float4(o[4], o[5], o[6], o[7]);
}

// invS[idx] = 1 / (sum over CHUNKS partials).
__global__ __launch_bounds__(256) void col_combine(const float* __restrict__ partial,
                                                   float* __restrict__ invS) {
  const int idx = blockIdx.x * 256 + threadIdx.x;  // b*Nn + j
  float s0 = 0.f, s1 = 0.f, s2 = 0.f, s3 = 0.f;
#pragma unroll
  for (int c = 0; c < CHUNKS; c += 4) {
    s0 += partial[(size_t)(c + 0) * (Bb * Nn) + idx];
    s1 += partial[(size_t)(c + 1) * (Bb * Nn) + idx];
    s2 += partial[(size_t)(c + 2) * (Bb * Nn) + idx];
    s3 += partial[(size_t)(c + 3) * (Bb * Nn) + idx];
  }
  invS[idx] = 1.f / ((s0 + s1) + (s2 + s3));
}

// out = exp(la) * rinv[i] * invS[j].
template<typename T>
__global__ __launch_bounds__(256) void finalize(const T* __restrict__ la,
                                                const float* __restrict__ rinv,
                                                const float* __restrict__ invS,
                                                float* __restrict__ out) {
  using v8 = typename V8<T>::type;
  const size_t g = (size_t)blockIdx.x * 256 + threadIdx.x;  // group of 8
  const size_t r = g >> 8;                        // 256 groups per row
  const int j8 = (int)(g & 255);
  const int b  = (int)(r >> 11);
  v8 v = ((const v8*)la)[g];
  const float rr = rinv[r];
  const float4* __restrict__ c4 = (const float4*)(invS + (size_t)b * Nn);
  float4 ca = c4[j8 * 2], cb = c4[j8 * 2 + 1];
  float4 o0, o1;
  o0.x = __expf((float)v[0]) * rr * ca.x;
  o0.y = __expf((float)v[1]) * rr * ca.y;
  o0.z = __expf((float)v[2]) * rr * ca.z;
  o0.w = __expf((float)v[3]) * rr * ca.w;
  o1.x = __expf((float)v[4]) * rr * cb.x;
  o1.y = __expf((float)v[5]) * rr * cb.y;
  o1.z = __expf((float)v[6]) * rr * cb.z;
  o1.w = __expf((float)v[7]) * rr * cb.w;
  ((float4*)out)[g * 2]     = o0;
  ((float4*)out)[g * 2 + 1] = o1;
}

template<typename T>
static void run_passes(const T* la, float* rinv, float* invS, float* partial,
                       float* out, hipStream_t stream) {
  const dim3 fGrid(CHUNKS, Bb);                  // 512 blocks
  const int ccBlocks = Bb * Nn / 256;            // 64
  const int fzBlocks = (int)(TOT / 8 / 256);     // 16384

  fused_pass<T, true><<<fGrid, 256, 0, stream>>>(la, invS, rinv, partial);
  col_combine<<<ccBlocks, 256, 0, stream>>>(partial, invS);
  for (int it = 1; it < 20; ++it) {
    fused_pass<T, false><<<fGrid, 256, 0, stream>>>(la, invS, rinv, partial);
    col_combine<<<ccBlocks, 256, 0, stream>>>(partial, invS);
  }
  finalize<T><<<fzBlocks, 256, 0, stream>>>(la, rinv, invS, out);
}

extern "C" void kernel_launch(void* const* d_in, const int* in_sizes, int n_in,
                              void* d_out, int out_size, void* d_ws, size_t ws_size,
                              hipStream_t stream) {
  const float* la0 = (const float*)d_in[0];
  float* out = (float*)d_out;

  const size_t la16_bytes = (size_t)TOT * 2;                 // 64 MB
  const size_t partial_floats = (size_t)CHUNKS * Bb * Nn;    // 1M floats, 4 MB
  const size_t need = la16_bytes + (2 * Bb * Nn + partial_floats) * 4 + 256;

  if (ws_size >= need) {
    _Float16* la16 = (_Float16*)d_ws;
    float* rinv = (float*)((char*)d_ws + la16_bytes);
    float* invS = rinv + Bb * Nn;
    float* partial = invS + Bb * Nn;
    convert_f16<<<(int)(TOT / 8 / 256), 256, 0, stream>>>(la0, la16);
    run_passes<_Float16>(la16, rinv, invS, partial, out, stream);
  } else {
    // fp32 fallback (no conversion buffer)
    float* rinv = (float*)d_ws;
    float* invS = rinv + Bb * Nn;
    float* partial = invS + Bb * Nn;
    run_passes<float>(la0, rinv, invS, partial, out, stream);
  }
}